// Round 1
// baseline (601.502 us; speedup 1.0000x reference)
//
#include <hip/hip_runtime.h>

// Problem constants (from reference)
#define Bx 256
#define Cc 9
#define NF 16
#define NT 16
#define Ee 192
// slabs = B*C*NF = 36864, each slab = one wave (4 x-rows x 64 floats -> 16 patches x 192)

__global__ __launch_bounds__(256) void patch_embed_kernel(
    const float* __restrict__ x,
    const float* __restrict__ W,
    const float* __restrict__ bias,
    const float* __restrict__ chan,
    const float* __restrict__ spat,
    const float* __restrict__ tpos,
    const float* __restrict__ fpos,
    const int*   __restrict__ sidx,
    float* __restrict__ out)
{
    const int lane = threadIdx.x & 63;
    const int wave = threadIdx.x >> 6;
    const int s = blockIdx.x * 4 + wave;      // slab index enumerating (b, c, f)

    const int bc = s >> 4;                    // b*C + c   (NF = 16)
    const int f  = s & 15;
    const int c  = bc % Cc;

    // Each lane owns e = lane, lane+64, lane+128
    // Load W rows (16 weights per e) into registers.
    float w[3][16];
#pragma unroll
    for (int j = 0; j < 3; ++j) {
        const float4* wp = (const float4*)(W + (size_t)(lane + j * 64) * 16);
#pragma unroll
        for (int u = 0; u < 4; ++u) {
            float4 t4 = wp[u];
            w[j][u * 4 + 0] = t4.x;
            w[j][u * 4 + 1] = t4.y;
            w[j][u * 4 + 2] = t4.z;
            w[j][u * 4 + 3] = t4.w;
        }
    }

    const int si = sidx[c];
    float base[3];
#pragma unroll
    for (int j = 0; j < 3; ++j) {
        int e = lane + j * 64;
        base[j] = bias[e] + chan[c * Ee + e] + spat[si * Ee + e] + fpos[f * Ee + e];
    }

    const float* xrow = x + ((size_t)bc * 64 + (size_t)f * 4) * 64;
    float* orow = out + (size_t)s * NT * Ee;

#pragma unroll 4
    for (int t = 0; t < NT; ++t) {
        // Wave-uniform x patch loads: 4 rows x 4 consecutive floats
        float4 xr[4];
#pragma unroll
        for (int u = 0; u < 4; ++u)
            xr[u] = *(const float4*)(xrow + u * 64 + t * 4);

        float acc[3];
#pragma unroll
        for (int j = 0; j < 3; ++j)
            acc[j] = base[j] + tpos[t * Ee + lane + j * 64];

#pragma unroll
        for (int j = 0; j < 3; ++j) {
#pragma unroll
            for (int u = 0; u < 4; ++u) {
                acc[j] += xr[u].x * w[j][u * 4 + 0];
                acc[j] += xr[u].y * w[j][u * 4 + 1];
                acc[j] += xr[u].z * w[j][u * 4 + 2];
                acc[j] += xr[u].w * w[j][u * 4 + 3];
            }
        }

        // Coalesced, streaming stores (no reuse of out -> keep L2 for tables)
#pragma unroll
        for (int j = 0; j < 3; ++j)
            __builtin_nontemporal_store(acc[j], orow + t * Ee + lane + j * 64);
    }
}

extern "C" void kernel_launch(void* const* d_in, const int* in_sizes, int n_in,
                              void* d_out, int out_size, void* d_ws, size_t ws_size,
                              hipStream_t stream) {
    const float* x    = (const float*)d_in[0];
    const float* W    = (const float*)d_in[1];
    const float* bias = (const float*)d_in[2];
    const float* chan = (const float*)d_in[3];
    const float* spat = (const float*)d_in[4];
    const float* tpos = (const float*)d_in[5];
    const float* fpos = (const float*)d_in[6];
    const int*   sidx = (const int*)d_in[7];
    float* out = (float*)d_out;

    const int slabs = Bx * Cc * NF;           // 36864
    dim3 grid(slabs / 4);                     // 4 waves (slabs) per 256-thread block
    dim3 block(256);
    patch_embed_kernel<<<grid, block, 0, stream>>>(x, W, bias, chan, spat, tpos, fpos, sidx, out);
}